// Round 1
// baseline (1158.841 us; speedup 1.0000x reference)
//
#include <hip/hip_runtime.h>
#include <math.h>

#define N_NODES 50000
#define N_EDGES 400000
#define FEAT    128
#define OUTF    384
#define N_RBF   20
#define CUTOFF  5.0f
#define PI_F    3.14159265358979f

// ---------------------------------------------------------------------------
// Node kernel: phi_nodes = silu(s_j @ W1 + b1) @ W2 + b2     (50000 x 384)
// 32 nodes per block, 256 threads. Each thread owns 1 column x 16 rows.
// ---------------------------------------------------------------------------
constexpr int TM = 32;

__global__ __launch_bounds__(256) void node_kernel(
    const float* __restrict__ s_j,
    const float* __restrict__ W1, const float* __restrict__ b1,
    const float* __restrict__ W2, const float* __restrict__ b2,
    float* __restrict__ phi)
{
    __shared__ float A[TM * FEAT];   // 16 KB
    __shared__ float H[TM * FEAT];   // 16 KB

    const int tid   = threadIdx.x;
    const int node0 = blockIdx.x * TM;

    // Load s_j tile (contiguous, coalesced). Guard tail block.
    for (int i = tid; i < TM * FEAT; i += 256) {
        int r = i >> 7;                      // i / 128
        A[i] = (node0 + r < N_NODES) ? s_j[(size_t)node0 * FEAT + i] : 0.f;
    }
    __syncthreads();

    const int c  = tid & 127;   // column 0..127
    const int rg = tid >> 7;    // row group 0/1 (rows rg*16 .. rg*16+15)

    // ---- GEMM 1: h = silu(A @ W1 + b1) ----
    float acc[16];
#pragma unroll
    for (int r = 0; r < 16; ++r) acc[r] = b1[c];

    for (int k = 0; k < FEAT; ++k) {
        float w = W1[k * FEAT + c];          // coalesced across lanes
#pragma unroll
        for (int r = 0; r < 16; ++r)
            acc[r] = fmaf(A[(rg * 16 + r) * FEAT + k], w, acc[r]);  // LDS broadcast
    }
#pragma unroll
    for (int r = 0; r < 16; ++r) {
        float x = acc[r];
        H[(rg * 16 + r) * FEAT + c] = x / (1.f + __expf(-x));       // silu
    }
    __syncthreads();

    // ---- GEMM 2: phi = H @ W2 + b2  (384 cols in 3 chunks of 128) ----
    for (int chunk = 0; chunk < 3; ++chunk) {
        const int c2 = chunk * 128 + c;
        float a2[16];
#pragma unroll
        for (int r = 0; r < 16; ++r) a2[r] = b2[c2];

        for (int k = 0; k < FEAT; ++k) {
            float w = W2[k * OUTF + c2];     // coalesced
#pragma unroll
            for (int r = 0; r < 16; ++r)
                a2[r] = fmaf(H[(rg * 16 + r) * FEAT + k], w, a2[r]);
        }
#pragma unroll
        for (int r = 0; r < 16; ++r) {
            int g = node0 + rg * 16 + r;
            if (g < N_NODES) phi[(size_t)g * OUTF + c2] = a2[r];
        }
    }
}

// ---------------------------------------------------------------------------
// Edge kernel: out[e, j] = phi[nbrs[e,1], j] * env(d) * (rbf(d) . Wd[:,j] + bd[j])
// 384 threads (1 per output column), 64 edges per block.
// Wd/bd staged in LDS; env is folded into the per-edge rbf vector.
// ---------------------------------------------------------------------------
constexpr int EPB = 64;

__global__ __launch_bounds__(384) void edge_kernel(
    const float* __restrict__ dist,
    const int*   __restrict__ nbrs,
    const float* __restrict__ Wd, const float* __restrict__ bd,
    const float* __restrict__ phi,
    float* __restrict__ out)
{
    __shared__ float sWd[N_RBF * OUTF];   // 30 KB
    __shared__ float sbd[OUTF];
    __shared__ float srbf[EPB][N_RBF];    // env-scaled rbf
    __shared__ float senv[EPB];
    __shared__ int   sidx[EPB];

    const int tid = threadIdx.x;
    const int e0  = blockIdx.x * EPB;

    for (int i = tid; i < N_RBF * OUTF; i += 384) sWd[i] = Wd[i];
    sbd[tid] = bd[tid];

    if (tid < EPB) {
        const int e = e0 + tid;
        if (e < N_EDGES) {
            float d = dist[e];
            sidx[tid] = nbrs[2 * e + 1];
            float env = (d < CUTOFF) ? 0.5f * (__cosf(PI_F * d * (1.0f / CUTOFF)) + 1.f) : 0.f;
            senv[tid] = env;
            float inv = (d == 0.f) ? 0.f : (env / d);
            const float w0 = PI_F * (1.0f / CUTOFF);
#pragma unroll
            for (int n = 0; n < N_RBF; ++n)
                srbf[tid][n] = __sinf((float)(n + 1) * w0 * d) * inv;
        } else {
            sidx[tid] = 0;
            senv[tid] = 0.f;
#pragma unroll
            for (int n = 0; n < N_RBF; ++n) srbf[tid][n] = 0.f;
        }
    }
    __syncthreads();

    const int nE  = min(EPB, N_EDGES - e0);
    const float bdj = sbd[tid];

    for (int e = 0; e < nE; ++e) {
        const float* pb = phi + (size_t)sidx[e] * OUTF;   // gather base (coalesced row)
        float w = senv[e] * bdj;
#pragma unroll
        for (int n = 0; n < N_RBF; ++n)
            w = fmaf(srbf[e][n], sWd[n * OUTF + tid], w);
        out[(size_t)(e0 + e) * OUTF + tid] = pb[tid] * w;
    }
}

// ---------------------------------------------------------------------------
extern "C" void kernel_launch(void* const* d_in, const int* in_sizes, int n_in,
                              void* d_out, int out_size, void* d_ws, size_t ws_size,
                              hipStream_t stream)
{
    const float* s_j  = (const float*)d_in[0];
    const float* dist = (const float*)d_in[1];
    const int*   nbrs = (const int*)  d_in[2];
    const float* W1   = (const float*)d_in[3];
    const float* b1   = (const float*)d_in[4];
    const float* W2   = (const float*)d_in[5];
    const float* b2   = (const float*)d_in[6];
    const float* Wd   = (const float*)d_in[7];
    const float* bd   = (const float*)d_in[8];

    float* out = (float*)d_out;
    float* phi = (float*)d_ws;    // 50000*384*4 = 76.8 MB scratch

    node_kernel<<<(N_NODES + TM - 1) / TM, 256, 0, stream>>>(s_j, W1, b1, W2, b2, phi);
    edge_kernel<<<(N_EDGES + EPB - 1) / EPB, 384, 0, stream>>>(dist, nbrs, Wd, bd, phi, out);
}